// Round 5
// baseline (270.703 us; speedup 1.0000x reference)
//
#include <hip/hip_runtime.h>
#include <cfloat>

#define NTOK (64 * 4096)   // 262144 tokens
#define HID  128
#define NE   64
#define TK   6
#define BLK  256
#define TPB  128           // tokens per block
#define GRID (NTOK / TPB)  // 2048 blocks
#define WST  68            // Wt row stride in floats (pad 64->68, keeps 16B align)
#define XOFF (HID * WST)   // 8704 floats: start of X-chunk / mz region
#define KC   16            // k per staged X chunk
#define NCH  (HID / KC)    // 8 chunks

// LDS plan (43008 B + 512 B):
//   phase GEMM : smem[0 .. 8704)        = Wt[k][e] at k*68+e (whole W, staged once)
//                smem[8704 .. 10752)    = X chunk, Xs[tok][16] with float4-granule
//                                         XOR swizzle (g ^ ((tok>>2)&3)) -> 2-way banks
//   phase EPI  : smem[0 .. 8704)        = logits L[tok][e] at tok*68+e  (reuse W)
//                smem[8704 .. 8960)     = mz[tok] = (max, 1/Z)          (reuse X)
__global__ __launch_bounds__(BLK, 3)
void gate_kernel(const float* __restrict__ X,
                 const float* __restrict__ W,
                 float* __restrict__ oidx,
                 float* __restrict__ ow,
                 float* __restrict__ Pi_g,
                 unsigned int* __restrict__ cnt_g)
{
    __shared__ float smem[XOFF + TPB * KC];
    __shared__ float        Pi_s[NE];
    __shared__ unsigned int cnt_s[NE];

    const int tid  = threadIdx.x;
    const int lane = tid & 63;
    const int wv   = tid >> 6;        // wave 0..3, each owns 32 tokens
    const int tg   = lane >> 3;       // token group 0..7
    const int eg   = lane & 7;        // expert group 0..7 -> experts 8eg..8eg+7
    const int sw   = tg & 3;          // x-read swizzle (matches staging swizzle)
    const int tokL0 = wv * 32 + tg * 4;        // this lane's 4 local tokens
    const int gtok0 = blockIdx.x * TPB;

    if (tid < NE) { Pi_s[tid] = 0.0f; cnt_s[tid] = 0u; }

    // ---- stage W -> LDS transposed: Wt[k][e] (one-time; conflicts negligible)
    {
        const float4* W4 = (const float4*)W;   // 2048 float4
#pragma unroll
        for (int i = 0; i < 8; ++i) {
            const int flat = tid + i * BLK;
            const float4 v = W4[flat];
            const int e = flat >> 5, k4 = flat & 31;
            smem[(4*k4+0)*WST + e] = v.x;
            smem[(4*k4+1)*WST + e] = v.y;
            smem[(4*k4+2)*WST + e] = v.z;
            smem[(4*k4+3)*WST + e] = v.w;
        }
    }

    float acc[4][8];
#pragma unroll
    for (int t = 0; t < 4; ++t)
#pragma unroll
        for (int j = 0; j < 8; ++j) acc[t][j] = 0.0f;

    const float4* X4 = (const float4*)X;

#pragma unroll 1
    for (int c = 0; c < NCH; ++c) {
        __syncthreads();   // W staged (c=0) / previous chunk's reads done (c>0)
        // ---- stage X chunk: 128 tok x 16 k, swizzled float4 granules
#pragma unroll
        for (int i = 0; i < 2; ++i) {
            const int flat  = tid + i * BLK;   // 0..511 float4s
            const int token = flat >> 2, g = flat & 3;
            const float4 v = X4[(size_t)(gtok0 + token) * (HID/4) + c*4 + g];
            *(float4*)&smem[XOFF + token*KC + ((g ^ ((token>>2)&3)) << 2)] = v;
        }
        __syncthreads();

        // ---- GEMM: 4 tok x 8 exp per lane; 12 ds_read per 128 FMA
        const float* wb = smem + c * KC * WST;
#pragma unroll
        for (int g = 0; g < 4; ++g) {
            float xs[4][4];
#pragma unroll
            for (int t = 0; t < 4; ++t) {
                const float4 v = *(const float4*)&smem[XOFF + (tokL0+t)*KC + ((g ^ sw) << 2)];
                xs[t][0] = v.x; xs[t][1] = v.y; xs[t][2] = v.z; xs[t][3] = v.w;
            }
#pragma unroll
            for (int j = 0; j < 4; ++j) {
                const float4 w0 = *(const float4*)&wb[(g*4+j)*WST + 8*eg];
                const float4 w1 = *(const float4*)&wb[(g*4+j)*WST + 8*eg + 4];
#pragma unroll
                for (int t = 0; t < 4; ++t) {
                    const float xv = xs[t][j];
                    acc[t][0] = fmaf(xv, w0.x, acc[t][0]);
                    acc[t][1] = fmaf(xv, w0.y, acc[t][1]);
                    acc[t][2] = fmaf(xv, w0.z, acc[t][2]);
                    acc[t][3] = fmaf(xv, w0.w, acc[t][3]);
                    acc[t][4] = fmaf(xv, w1.x, acc[t][4]);
                    acc[t][5] = fmaf(xv, w1.y, acc[t][5]);
                    acc[t][6] = fmaf(xv, w1.z, acc[t][6]);
                    acc[t][7] = fmaf(xv, w1.w, acc[t][7]);
                }
            }
        }
    }

    __syncthreads();   // all GEMM reads done -> W region reusable

    // ---- scatter logits: L[tok][e] = smem[tok*68 + e]
#pragma unroll
    for (int t = 0; t < 4; ++t) {
        *(float4*)&smem[(tokL0+t)*WST + 8*eg    ] =
            make_float4(acc[t][0], acc[t][1], acc[t][2], acc[t][3]);
        *(float4*)&smem[(tokL0+t)*WST + 8*eg + 4] =
            make_float4(acc[t][4], acc[t][5], acc[t][6], acc[t][7]);
    }
    __syncthreads();

    // ---- thread = token: streaming top-6 + outputs + (mx, 1/Z)
    if (tid < TPB) {
        const int t = tid;
        const float* Lrow = &smem[t * WST];
        float tv[TK]; int ti[TK];
#pragma unroll
        for (int q = 0; q < TK; ++q) { tv[q] = -FLT_MAX; ti[q] = 0; }

#pragma unroll 4
        for (int e4 = 0; e4 < 16; ++e4) {
            const float4 v4 = *(const float4*)&Lrow[e4 * 4];
            const float vv[4] = {v4.x, v4.y, v4.z, v4.w};
#pragma unroll
            for (int u = 0; u < 4; ++u) {
                float m = vv[u]; int mi = e4*4 + u;   // ascending e: stable ties
#pragma unroll
                for (int q = 0; q < TK; ++q) {
                    const bool  cx = m > tv[q];
                    const float nt = cx ? m     : tv[q];
                    const float nm = cx ? tv[q] : m;
                    const int   ni = cx ? mi    : ti[q];
                    const int   nj = cx ? ti[q] : mi;
                    tv[q] = nt; m = nm; ti[q] = ni; mi = nj;
                }
            }
        }

        const float mx = tv[0];
        float ex[TK]; float s = 0.0f;
#pragma unroll
        for (int q = 0; q < TK; ++q) { ex[q] = __expf(tv[q] - mx); s += ex[q]; }
        const float rs = 1.0f / (s + 1e-20f);

        const size_t gt = (size_t)(gtok0 + t) * TK;
        float2* ip = (float2*)(oidx + gt);
        float2* wp = (float2*)(ow + gt);
        ip[0] = make_float2((float)ti[0], (float)ti[1]);
        ip[1] = make_float2((float)ti[2], (float)ti[3]);
        ip[2] = make_float2((float)ti[4], (float)ti[5]);
        wp[0] = make_float2(ex[0]*rs, ex[1]*rs);
        wp[1] = make_float2(ex[2]*rs, ex[3]*rs);
        wp[2] = make_float2(ex[4]*rs, ex[5]*rs);

#pragma unroll
        for (int q = 0; q < TK; ++q) atomicAdd(&cnt_s[ti[q]], 1u);

        float Z = 0.0f;
#pragma unroll 4
        for (int e4 = 0; e4 < 16; ++e4) {
            const float4 v4 = *(const float4*)&Lrow[e4 * 4];
            Z += __expf(v4.x - mx); Z += __expf(v4.y - mx);
            Z += __expf(v4.z - mx); Z += __expf(v4.w - mx);
        }
        smem[XOFF + 2*t]     = mx;
        smem[XOFF + 2*t + 1] = 1.0f / Z;
    }
    __syncthreads();

    // ---- Pi partials in GEMM register layout (acc still holds raw logits)
    float pi[8];
#pragma unroll
    for (int j = 0; j < 8; ++j) pi[j] = 0.0f;
#pragma unroll
    for (int t = 0; t < 4; ++t) {
        const float mxt = smem[XOFF + 2*(tokL0+t)];
        const float rzt = smem[XOFF + 2*(tokL0+t) + 1];
#pragma unroll
        for (int j = 0; j < 8; ++j)
            pi[j] += __expf(acc[t][j] - mxt) * rzt;
    }
#pragma unroll
    for (int j = 0; j < 8; ++j) atomicAdd(&Pi_s[8*eg + j], pi[j]);

    __syncthreads();
    if (tid < NE) {
        atomicAdd(&Pi_g[tid], Pi_s[tid]);
        atomicAdd(&cnt_g[tid], cnt_s[tid]);
    }
}

__global__ void aux_kernel(const float* __restrict__ Pi_g,
                           const unsigned int* __restrict__ cnt_g,
                           float* __restrict__ out_aux)
{
    const int e = threadIdx.x;   // 64 threads
    const float Pi = Pi_g[e] * (1.0f / (float)NTOK);
    const float ce = (float)cnt_g[e] * (1.0f / (float)(NTOK * TK));
    float v = Pi * ce * (float)NE;
#pragma unroll
    for (int off = 32; off > 0; off >>= 1) v += __shfl_down(v, off);
    if (e == 0) out_aux[0] = v * 1.0e-3f;
}

extern "C" void kernel_launch(void* const* d_in, const int* in_sizes, int n_in,
                              void* d_out, int out_size, void* d_ws, size_t ws_size,
                              hipStream_t stream) {
    const float* X = (const float*)d_in[0];
    const float* W = (const float*)d_in[1];

    float* out  = (float*)d_out;
    float* oidx = out;                          // N*6 indices (as float)
    float* ow   = out + (size_t)NTOK * TK;      // N*6 weights
    float* aux  = out + (size_t)NTOK * TK * 2;  // 1 scalar

    float*        Pi_g  = (float*)d_ws;
    unsigned int* cnt_g = (unsigned int*)((char*)d_ws + 256);

    hipMemsetAsync(d_ws, 0, 512, stream);
    gate_kernel<<<GRID, BLK, 0, stream>>>(X, W, oidx, ow, Pi_g, cnt_g);
    aux_kernel<<<1, 64, 0, stream>>>(Pi_g, cnt_g, aux);
}